// Round 8
// baseline (1539.585 us; speedup 1.0000x reference)
//
#include <hip/hip_runtime.h>
#include <hip/hip_bf16.h>
#include <hip/hip_cooperative_groups.h>

namespace cg = cooperative_groups;

#define N_NODESC 50000
#define N_EDGESC 800000
#define DD 128
#define HH 8
#define HDIM 16
#define N_NT 3
#define N_ET 5
#define NPB 196    // permutation chunks (196*256 = 50176 >= 50000)
#define NBLK 1536  // cooperative grid (<= 2048 co-resident at 4 waves/block)

// ---------------- workspace layout (bytes), total ~91.6 MB ----------------
#define KV8_OFF    ((size_t)0)           // fp8 [N][128] {K,V} interleaved ushort, 12.8 MB
#define QT8_OFF    ((size_t)12800000)    // fp8 [N][640] 32 MB (dead after edgeagg)
#define XP_OFF     ((size_t)44800000)    // bf16 [N][128] permuted 12.8 MB (dead after proj)
#define T_OFF      ((size_t)0)           // bf16 [N][512] 51.2 MB overlays KV8|Qt8|Xp (dead at ffn1)
#define AGG_OFF    ((size_t)57600000)    // bf16 [N][128] 12.8 MB
#define H1B_OFF    ((size_t)70400000)    // bf16 [N][128] 12.8 MB
#define WOUTT_OFF  ((size_t)83200000)    // bf16 [128][128] 32 KB
#define W1T_OFF    ((size_t)83232768)    // bf16 [512][128] 128 KB
#define W2T_OFF    ((size_t)83363840)    // bf16 [128][512] 128 KB
#define WALL_OFF   ((size_t)83494912)    // bf16 [3][896][128] 672 KB
#define EDATA_OFF  ((size_t)84183040)    // int [E] packed src|et<<16, 3.2 MB
#define ROWS_OFF   ((size_t)87383040)    // int [N+1] (+pad)
#define ORIG_OFF   ((size_t)87583104)    // int [N]
#define NEWOF_OFF  ((size_t)87783104)    // int [N]
#define DEG_OFF    ((size_t)87983104)    // int [N]
#define TOFS_OFF   ((size_t)88183104)    // int [4]
#define BH_OFF     ((size_t)88183168)    // int [3*NPB]
#define BB_OFF     ((size_t)88185536)    // int [3*NPB]
#define BSUM_OFF   ((size_t)88187904)    // int [NPB] (+pad)
#define TMP_OFF    ((size_t)88188928)    // uint [E] packed rank<<16|nd, 3.2 MB

using short8 = __attribute__((ext_vector_type(8))) short;
using f32x4  = __attribute__((ext_vector_type(4))) float;

__device__ __forceinline__ ushort f2b(float f) {
    __hip_bfloat16 h = __float2bfloat16(f);
    return *(ushort*)&h;
}
__device__ __forceinline__ float b2f(ushort u) {
    __hip_bfloat16 h = *(__hip_bfloat16*)&u;
    return __bfloat162float(h);
}

// ---------------- fused weight prep: Woutt | W1t | W2t | Wall (Wc inline) ----------------
__global__ __launch_bounds__(256) void wprep_kernel(
    const float* __restrict__ Wout, const float* __restrict__ W1, const float* __restrict__ W2,
    const float* __restrict__ WQ, const float* __restrict__ Wk, const float* __restrict__ Wv,
    const float* __restrict__ We, const float* __restrict__ mu,
    ushort* __restrict__ Woutt, ushort* __restrict__ W1t, ushort* __restrict__ W2t,
    ushort* __restrict__ Wall)
{
    const int gid = blockIdx.x * 256 + threadIdx.x;
    if (gid < 16384) {                       // Woutt[n][k] = Wout[k][n]
        const int nn = gid >> 7, k = gid & 127;
        Woutt[gid] = f2b(Wout[k * 128 + nn]);
    } else if (gid < 81920) {                // W1t[n][k] = W1[k][n]
        const int i = gid - 16384;
        const int nn = i >> 7, k = i & 127;
        W1t[i] = f2b(W1[k * 512 + nn]);
    } else if (gid < 147456) {               // W2t[n][k] = W2[k][n]
        const int i = gid - 81920;
        const int nn = i >> 9, k = i & 511;
        W2t[i] = f2b(W2[k * 128 + nn]);
    } else {                                 // Wall
        const int idx = gid - 147456;        // < 3*896*128 = 344064
        const int t = idx / (896 * 128);
        const int rem = idx % (896 * 128);
        const int c = rem / 128, k = rem % 128;
        const int hk = k >> 4, ck = k & 15;
        float v = 0.f;
        if (c < 128) {
            const int hc = c >> 4, j = c & 15;
            if (hk == hc) v = 4.f * Wk[((t * HH + hc) * HDIM + ck) * HDIM + j];
        } else if (c < 256) {
            const int c2 = c - 128, hc = c2 >> 4, j = c2 & 15;
            if (hk == hc) v = 4.f * Wv[((t * HH + hc) * HDIM + ck) * HDIM + j];
        } else {
            const int cq = c - 256, et = cq >> 7, dd = cq & 127;
            const int hq = dd >> 4, j = dd & 15;
            if (hk == hq) {
                const float* wq = WQ + ((t * HH + hq) * HDIM + ck) * HDIM;
                const float* we = We + ((et * HH + hq) * HDIM + j) * HDIM;
                float s = 0.f;
#pragma unroll
                for (int f = 0; f < 16; f++) s = fmaf(wq[f], we[f], s);
                v = 64.f * mu[hq * N_ET + et] * s;
            }
        }
        Wall[idx] = f2b(v);
    }
}

// ---------------- cooperative prep: perm sort + Xp + CSR (single-atomic-pass) ----------------
__global__ __launch_bounds__(256) void coop_prep(
    const int* __restrict__ ntype, const float* __restrict__ x,
    const int* __restrict__ src, const int* __restrict__ dst, const int* __restrict__ etype,
    int* __restrict__ deg, unsigned int* __restrict__ tmp,
    int* __restrict__ bh, int* __restrict__ bb,
    int* __restrict__ tofs, int* __restrict__ bsum,
    int* __restrict__ origof, int* __restrict__ newof, ushort* __restrict__ Xp,
    int* __restrict__ rows, int* __restrict__ edata)
{
    cg::grid_group grid = cg::this_grid();
    const int b = blockIdx.x, tid = threadIdx.x;
    const int gthread = b * 256 + tid;
    const int wave = tid >> 6, lane = tid & 63;
    __shared__ int lscan[256];
    __shared__ int wcnt[4][3];

    // ---- A: zero deg (grid-stride) + per-chunk type histogram (chunk = block < NPB) ----
    for (int i = gthread; i < N_NODESC; i += NBLK * 256) deg[i] = 0;
    int t = -1;
    if (b < NPB) {
        const int n = b * 256 + tid;
        t = (n < N_NODESC) ? ntype[n] : -1;
        const unsigned long long m0 = __ballot(t == 0);
        const unsigned long long m1 = __ballot(t == 1);
        const unsigned long long m2 = __ballot(t == 2);
        if (lane == 0) {
            wcnt[wave][0] = (int)__popcll(m0);
            wcnt[wave][1] = (int)__popcll(m1);
            wcnt[wave][2] = (int)__popcll(m2);
        }
        __syncthreads();
        if (tid < 3)
            bh[tid * NPB + b] = wcnt[0][tid] + wcnt[1][tid] + wcnt[2][tid] + wcnt[3][tid];
    }
    grid.sync();

    // ---- B: block 0 scans 3*NPB=588 entries -> bb (exclusive), tofs ----
    if (b == 0) {
        const int base3 = tid * 3;
        int e0 = (base3 + 0 < 588) ? bh[base3 + 0] : 0;
        int e1 = (base3 + 1 < 588) ? bh[base3 + 1] : 0;
        int e2 = (base3 + 2 < 588) ? bh[base3 + 2] : 0;
        const int l0 = e0, l1 = e0 + e1, l2 = l1 + e2;
        lscan[tid] = l2;
        __syncthreads();
        for (int off = 1; off < 256; off <<= 1) {
            const int u = (tid >= off) ? lscan[tid - off] : 0;
            __syncthreads();
            lscan[tid] += u;
            __syncthreads();
        }
        const int tb = lscan[tid] - l2;
        if (base3 + 0 < 588) bb[base3 + 0] = tb;
        if (base3 + 1 < 588) bb[base3 + 1] = tb + l0;
        if (base3 + 2 < 588) bb[base3 + 2] = tb + l1;
        __syncthreads();
        if (tid == 0) {
            tofs[0] = 0;
            tofs[1] = bb[NPB];
            tofs[2] = bb[2 * NPB];
            tofs[3] = N_NODESC;
        }
    }
    grid.sync();

    // ---- C: stable scatter -> origof/newof (chunk = block < NPB) ----
    if (b < NPB) {
        const int n = b * 256 + tid;
        const unsigned long long m0 = __ballot(t == 0);
        const unsigned long long m1 = __ballot(t == 1);
        const unsigned long long m2 = __ballot(t == 2);
        if (n < N_NODESC) {
            int basew = 0;
#pragma unroll
            for (int w = 0; w < 4; w++) if (w < wave) basew += wcnt[w][t];
            const unsigned long long mt = (t == 0) ? m0 : (t == 1) ? m1 : m2;
            const unsigned long long mlt = ((unsigned long long)1 << lane) - 1;
            const int p = bb[t * NPB + b] + basew + (int)__popcll(mt & mlt);
            origof[p] = n;
            newof[n] = p;
        }
    }
    grid.sync();

    // ---- D: Xp permuted bf16 copy + deg atomic (rank returned, packed to tmp) ----
    for (int gid = gthread; gid < N_NODESC * 16; gid += NBLK * 256) {
        const int n = gid >> 4, c = (gid & 15) << 3;
        const float4 v0 = *(const float4*)(x + (size_t)n * DD + c);
        const float4 v1 = *(const float4*)(x + (size_t)n * DD + c + 4);
        ushort o[8] = {f2b(v0.x), f2b(v0.y), f2b(v0.z), f2b(v0.w),
                       f2b(v1.x), f2b(v1.y), f2b(v1.z), f2b(v1.w)};
        const int p = newof[n];
        *(uint4*)(Xp + (size_t)p * DD + c) = *(uint4*)o;
    }
    for (int e = gthread; e < N_EDGESC; e += NBLK * 256) {
        const int nd = newof[dst[e]];
        const unsigned int p = (unsigned int)atomicAdd(&deg[nd], 1);
        tmp[e] = (p << 16) | (unsigned int)nd;
    }
    grid.sync();

    // ---- E1: per-chunk scan of deg ----
    int rexcl = 0, vdeg = 0;
    if (b < NPB) {
        const int n = b * 256 + tid;
        vdeg = (n < N_NODESC) ? deg[n] : 0;
        __syncthreads();
        lscan[tid] = vdeg;
        __syncthreads();
        for (int off = 1; off < 256; off <<= 1) {
            const int u = (tid >= off) ? lscan[tid - off] : 0;
            __syncthreads();
            lscan[tid] += u;
            __syncthreads();
        }
        rexcl = lscan[tid] - vdeg;
        if (tid == 0) bsum[b] = lscan[255];
    }
    grid.sync();

    // ---- E2: block 0 scans block sums -> exclusive ----
    if (b == 0) {
        const int lv = (tid < NPB) ? bsum[tid] : 0;
        __syncthreads();
        lscan[tid] = lv;
        __syncthreads();
        for (int off = 1; off < 256; off <<= 1) {
            const int u = (tid >= off) ? lscan[tid - off] : 0;
            __syncthreads();
            lscan[tid] += u;
            __syncthreads();
        }
        if (tid < NPB) bsum[tid] = lscan[tid] - lv;
        if (tid == 0) rows[N_NODESC] = lscan[255];
    }
    grid.sync();

    // ---- E3: rows = block base + local exclusive ----
    if (b < NPB) {
        const int n = b * 256 + tid;
        if (n < N_NODESC) rows[n] = bsum[b] + rexcl;
    }
    grid.sync();

    // ---- F: fill edata (atomic-free: rank from tmp) ----
    for (int e = gthread; e < N_EDGESC; e += NBLK * 256) {
        const unsigned int v = tmp[e];
        const int nd = (int)(v & 0xffffu);
        const int p = (int)(v >> 16);
        edata[rows[nd] + p] = newof[src[e]] | (etype[e] << 16);
    }
}

// ---------------- projection GEMM: Xp @ Wall[t] -> KV8 (interleaved) | Qt8 ----------------
#define LDP 40

__global__ __launch_bounds__(256) void proj_gemm(
    const ushort* __restrict__ Xp, const ushort* __restrict__ Wall,
    const int* __restrict__ tofs,
    ushort* __restrict__ KV8, unsigned char* __restrict__ Qt8)
{
    const int t = blockIdx.z;
    const int rs = tofs[t], re = tofs[t + 1];
    const int mBase = rs + blockIdx.x * 128;
    if (mBase >= re) return;
    const int nBase = blockIdx.y * 128;
    const ushort* Bt = Wall + (size_t)t * 896 * 128;

    __shared__ ushort As[128 * LDP];
    __shared__ ushort Bs[128 * LDP];
    const int tid = threadIdx.x;
    const int lane = tid & 63, wave = tid >> 6;
    const int mw = (wave >> 1) * 64, nw = (wave & 1) * 64;
    const int l15 = lane & 15, q8 = (lane >> 4) * 8;

    f32x4 acc[4][4];
#pragma unroll
    for (int i = 0; i < 4; i++)
#pragma unroll
        for (int j = 0; j < 4; j++) acc[i][j] = (f32x4){0.f, 0.f, 0.f, 0.f};

    const int r0 = tid >> 2, c0 = (tid & 3) * 8;
    int rA0 = mBase + r0;      if (rA0 >= N_NODESC) rA0 = N_NODESC - 1;
    int rA1 = mBase + r0 + 64; if (rA1 >= N_NODESC) rA1 = N_NODESC - 1;

    for (int kk = 0; kk < 128; kk += 32) {
        short8 a0 = *(const short8*)(Xp + (size_t)rA0 * DD + kk + c0);
        short8 a1 = *(const short8*)(Xp + (size_t)rA1 * DD + kk + c0);
        short8 b0 = *(const short8*)(Bt + (size_t)(nBase + r0) * 128 + kk + c0);
        short8 b1 = *(const short8*)(Bt + (size_t)(nBase + r0 + 64) * 128 + kk + c0);
        *(short8*)&As[r0 * LDP + c0] = a0;
        *(short8*)&As[(r0 + 64) * LDP + c0] = a1;
        *(short8*)&Bs[r0 * LDP + c0] = b0;
        *(short8*)&Bs[(r0 + 64) * LDP + c0] = b1;
        __syncthreads();
        short8 af[4], bf[4];
#pragma unroll
        for (int i = 0; i < 4; i++)
            af[i] = *(const short8*)&As[(mw + i * 16 + l15) * LDP + q8];
#pragma unroll
        for (int j = 0; j < 4; j++)
            bf[j] = *(const short8*)&Bs[(nw + j * 16 + l15) * LDP + q8];
#pragma unroll
        for (int i = 0; i < 4; i++)
#pragma unroll
            for (int j = 0; j < 4; j++)
                acc[i][j] = __builtin_amdgcn_mfma_f32_16x16x32_bf16(af[i], bf[j], acc[i][j], 0, 0, 0);
        __syncthreads();
    }

    unsigned char* kvb = (unsigned char*)KV8;
    const int rq = (lane >> 4) * 4;
#pragma unroll
    for (int i = 0; i < 4; i++) {
#pragma unroll
        for (int r = 0; r < 4; r++) {
            const int gm = mBase + mw + i * 16 + rq + r;
            if (gm >= re) continue;
#pragma unroll
            for (int j = 0; j < 4; j++) {
                const int gn = nBase + nw + j * 16 + l15;
                const float v = acc[i][j][r];
                const unsigned char b8 =
                    (unsigned char)(__builtin_amdgcn_cvt_pk_fp8_f32(v, v, 0, false) & 0xff);
                if (gn < 128)      kvb[(size_t)gm * 256 + gn * 2] = b8;             // K byte0
                else if (gn < 256) kvb[(size_t)gm * 256 + (gn - 128) * 2 + 1] = b8; // V byte1
                else               Qt8[(size_t)gm * 640 + (gn - 256)] = b8;
            }
        }
    }
}

// ---------------- fused edge pass: 1 ushort gather/edge, LDS q table, exp2 ----------------
#define PROC(ed) { \
    const int s_ = (ed) & 0xffff; \
    const int et_ = (ed) >> 16; \
    const ushort kv_ = KV8[((size_t)s_ << 7) + f]; \
    const float k_ = __builtin_amdgcn_cvt_f32_fp8((int)kv_, 0); \
    const float v_ = __builtin_amdgcn_cvt_f32_fp8((int)kv_, 1); \
    float p_ = qs[(et_ << 7) + f] * k_; \
    p_ += __shfl_xor(p_, 1); p_ += __shfl_xor(p_, 2); \
    p_ += __shfl_xor(p_, 4); p_ += __shfl_xor(p_, 8); \
    const float ex_ = exp2f(p_); \
    den += ex_; acc = fmaf(ex_, v_, acc); }

__global__ __launch_bounds__(128) void edgeagg_kernel(
    const int* __restrict__ rowstart, const int* __restrict__ edata,
    const unsigned char* __restrict__ Qt8, const ushort* __restrict__ KV8,
    const int* __restrict__ origof, ushort* __restrict__ agg)
{
    const int n = blockIdx.x;
    const int f = threadIdx.x;
    __shared__ float qs[N_ET * DD];
    const float qscale = 1.44269504f / 1024.f;
#pragma unroll
    for (int et = 0; et < N_ET; et++)
        qs[(et << 7) + f] =
            __builtin_amdgcn_cvt_f32_fp8((int)Qt8[(size_t)n * 640 + (et << 7) + f], 0) * qscale;
    __syncthreads();

    const int s0 = rowstart[n], s1 = rowstart[n + 1];
    float acc = 0.f, den = 0.f;
    int i = s0;
    for (; i + 3 < s1; i += 4) {
        const int e0 = edata[i], e1 = edata[i + 1], e2 = edata[i + 2], e3 = edata[i + 3];
        PROC(e0); PROC(e1); PROC(e2); PROC(e3);
    }
    for (; i < s1; i++) { const int e0 = edata[i]; PROC(e0); }
    agg[(size_t)origof[n] * DD + f] = f2b(0.25f * acc / (den + 1e-10f));
}

// ---------------- MFMA bf16 GEMM 128x128 tile, BK=32, fused epilogues ----------------
template<int KT, int EPI>
__global__ __launch_bounds__(256) void mfma_gemm(
    const ushort* __restrict__ A, const ushort* __restrict__ Bt,
    const float* __restrict__ bias,
    const float* __restrict__ residF, const ushort* __restrict__ residB,
    const float* __restrict__ g, const float* __restrict__ b,
    float* __restrict__ outF, ushort* __restrict__ outB, int ldOut)
{
    __shared__ ushort As[128 * LDP];
    __shared__ ushort Bs[128 * LDP];
    __shared__ float red[2][2][128];
    const int tid = threadIdx.x;
    const int lane = tid & 63, wave = tid >> 6;
    const int mw = (wave >> 1) * 64, nw = (wave & 1) * 64;
    const int mBase = blockIdx.x * 128, nBase = blockIdx.y * 128;
    const int l15 = lane & 15, q8 = (lane >> 4) * 8;

    f32x4 acc[4][4];
#pragma unroll
    for (int i = 0; i < 4; i++)
#pragma unroll
        for (int j = 0; j < 4; j++) acc[i][j] = (f32x4){0.f, 0.f, 0.f, 0.f};

    const int r0 = tid >> 2;
    const int c0 = (tid & 3) * 8;

    for (int kk = 0; kk < KT; kk += 32) {
        const ushort* pa = A  + (size_t)(mBase + r0) * KT + kk + c0;
        const ushort* pb = Bt + (size_t)(nBase + r0) * KT + kk + c0;
        short8 a0 = *(const short8*)pa;
        short8 a1 = *(const short8*)(pa + (size_t)64 * KT);
        short8 b0 = *(const short8*)pb;
        short8 b1 = *(const short8*)(pb + (size_t)64 * KT);
        *(short8*)&As[r0 * LDP + c0] = a0;
        *(short8*)&As[(r0 + 64) * LDP + c0] = a1;
        *(short8*)&Bs[r0 * LDP + c0] = b0;
        *(short8*)&Bs[(r0 + 64) * LDP + c0] = b1;
        __syncthreads();

        short8 af[4], bf[4];
#pragma unroll
        for (int i = 0; i < 4; i++)
            af[i] = *(const short8*)&As[(mw + i * 16 + l15) * LDP + q8];
#pragma unroll
        for (int j = 0; j < 4; j++)
            bf[j] = *(const short8*)&Bs[(nw + j * 16 + l15) * LDP + q8];
#pragma unroll
        for (int i = 0; i < 4; i++)
#pragma unroll
            for (int j = 0; j < 4; j++)
                acc[i][j] = __builtin_amdgcn_mfma_f32_16x16x32_bf16(af[i], bf[j], acc[i][j], 0, 0, 0);
        __syncthreads();
    }

    const int rq = (lane >> 4) * 4;

    if (EPI == 0) {
#pragma unroll
        for (int i = 0; i < 4; i++) {
#pragma unroll
            for (int r = 0; r < 4; r++) {
                const int gm = mBase + mw + i * 16 + rq + r;
                if (gm >= N_NODESC) continue;
#pragma unroll
                for (int j = 0; j < 4; j++) {
                    const int gn = nBase + nw + j * 16 + l15;
                    float v = acc[i][j][r] + bias[gn];
                    v = 0.5f * v * (1.f + erff(v * 0.70710678118654752f));
                    outB[(size_t)gm * ldOut + gn] = f2b(v);
                }
            }
        }
    } else {
        float biasv[4], gv[4], bv[4];
#pragma unroll
        for (int j = 0; j < 4; j++) {
            const int gn = nw + j * 16 + l15;
            biasv[j] = bias[gn]; gv[j] = g[gn]; bv[j] = b[gn];
        }
#pragma unroll
        for (int i = 0; i < 4; i++) {
#pragma unroll
            for (int r = 0; r < 4; r++) {
                const int row = mw + i * 16 + rq + r;
                const int gm = mBase + row;
                float s = 0.f, ss = 0.f;
#pragma unroll
                for (int j = 0; j < 4; j++) {
                    const int gn = nw + j * 16 + l15;
                    float v = acc[i][j][r] + biasv[j];
                    if (EPI == 1) v += (gm < N_NODESC) ? residF[(size_t)gm * DD + gn] : 0.f;
                    else          v += (gm < N_NODESC) ? b2f(residB[(size_t)gm * DD + gn]) : 0.f;
                    acc[i][j][r] = v;
                    s += v; ss += v * v;
                }
                s  += __shfl_xor(s, 1);  s  += __shfl_xor(s, 2);  s  += __shfl_xor(s, 4);  s  += __shfl_xor(s, 8);
                ss += __shfl_xor(ss, 1); ss += __shfl_xor(ss, 2); ss += __shfl_xor(ss, 4); ss += __shfl_xor(ss, 8);
                if (l15 == 0) { red[0][nw >> 6][row] = s; red[1][nw >> 6][row] = ss; }
            }
        }
        __syncthreads();
#pragma unroll
        for (int i = 0; i < 4; i++) {
#pragma unroll
            for (int r = 0; r < 4; r++) {
                const int row = mw + i * 16 + rq + r;
                const int gm = mBase + row;
                if (gm >= N_NODESC) continue;
                const float s  = red[0][0][row] + red[0][1][row];
                const float ss = red[1][0][row] + red[1][1][row];
                const float mean = s * (1.f / 128.f);
                const float var  = ss * (1.f / 128.f) - mean * mean;
                const float rstd = rsqrtf(var + 1e-5f);
#pragma unroll
                for (int j = 0; j < 4; j++) {
                    const int gn = nw + j * 16 + l15;
                    const float o = (acc[i][j][r] - mean) * rstd * gv[j] + bv[j];
                    if (EPI == 1) outB[(size_t)gm * DD + gn] = f2b(o);
                    else          outF[(size_t)gm * DD + gn] = o;
                }
            }
        }
    }
}

extern "C" void kernel_launch(void* const* d_in, const int* in_sizes, int n_in,
                              void* d_out, int out_size, void* d_ws, size_t ws_size,
                              hipStream_t stream)
{
    const float* x     = (const float*)d_in[0];
    const int*   ei    = (const int*)d_in[1];
    const int*   etyp  = (const int*)d_in[2];
    const int*   ntype = (const int*)d_in[3];
    const float* Wq    = (const float*)d_in[4];
    const float* Wk    = (const float*)d_in[5];
    const float* Wv    = (const float*)d_in[6];
    const float* We    = (const float*)d_in[7];
    const float* mu    = (const float*)d_in[8];
    const float* Wout  = (const float*)d_in[9];
    const float* bout  = (const float*)d_in[10];
    const float* g1    = (const float*)d_in[11];
    const float* b1ln  = (const float*)d_in[12];
    const float* W1    = (const float*)d_in[13];
    const float* b1    = (const float*)d_in[14];
    const float* W2    = (const float*)d_in[15];
    const float* b2    = (const float*)d_in[16];
    const float* g2    = (const float*)d_in[17];
    const float* b2ln  = (const float*)d_in[18];
    float* out = (float*)d_out;

    char* ws = (char*)d_ws;
    ushort*        KV8   = (ushort*)(ws + KV8_OFF);
    unsigned char* Qt8   = (unsigned char*)(ws + QT8_OFF);
    ushort*        Xp    = (ushort*)(ws + XP_OFF);
    ushort*        T     = (ushort*)(ws + T_OFF);
    ushort*        agg   = (ushort*)(ws + AGG_OFF);
    ushort*        h1b   = (ushort*)(ws + H1B_OFF);
    ushort*        Woutt = (ushort*)(ws + WOUTT_OFF);
    ushort*        W1t   = (ushort*)(ws + W1T_OFF);
    ushort*        W2t   = (ushort*)(ws + W2T_OFF);
    ushort*        Wall  = (ushort*)(ws + WALL_OFF);
    int*           edata = (int*)(ws + EDATA_OFF);
    int*           rows  = (int*)(ws + ROWS_OFF);
    int*           origof= (int*)(ws + ORIG_OFF);
    int*           newof = (int*)(ws + NEWOF_OFF);
    int*           deg   = (int*)(ws + DEG_OFF);
    int*           tofs  = (int*)(ws + TOFS_OFF);
    int*           bh    = (int*)(ws + BH_OFF);
    int*           bb    = (int*)(ws + BB_OFF);
    int*           bsum  = (int*)(ws + BSUM_OFF);
    unsigned int*  tmp   = (unsigned int*)(ws + TMP_OFF);

    const int* srcA = ei;
    const int* dstA = ei + N_EDGESC;

    wprep_kernel<<<1920, 256, 0, stream>>>(Wout, W1, W2, Wq, Wk, Wv, We, mu,
                                           Woutt, W1t, W2t, Wall);

    void* cargs[] = { (void*)&ntype, (void*)&x, (void*)&srcA, (void*)&dstA, (void*)&etyp,
                      (void*)&deg, (void*)&tmp, (void*)&bh, (void*)&bb, (void*)&tofs,
                      (void*)&bsum, (void*)&origof, (void*)&newof, (void*)&Xp,
                      (void*)&rows, (void*)&edata };
    (void)hipLaunchCooperativeKernel((const void*)coop_prep, dim3(NBLK), dim3(256),
                                     cargs, 0, stream);

    proj_gemm<<<dim3(394, 7, 3), 256, 0, stream>>>(Xp, Wall, tofs, KV8, Qt8);
    edgeagg_kernel<<<N_NODESC, 128, 0, stream>>>(rows, edata, Qt8, KV8, origof, agg);

    // h1b = LN1(agg @ Wout + bout + x)  (bf16)
    mfma_gemm<128, 1><<<391, 256, 0, stream>>>(agg, Woutt, bout, x, nullptr, g1, b1ln, nullptr, h1b, 128);
    // T = gelu(h1b @ W1 + b1)  (bf16)
    mfma_gemm<128, 0><<<dim3(391, 4), 256, 0, stream>>>(h1b, W1t, b1, nullptr, nullptr, nullptr, nullptr, nullptr, T, 512);
    // out = LN2(T @ W2 + b2 + h1b)  (f32)
    mfma_gemm<512, 2><<<391, 256, 0, stream>>>(T, W2t, b2, nullptr, h1b, g2, b2ln, out, nullptr, 128);
}

// Round 9
// 495.226 us; speedup vs baseline: 3.1089x; 3.1089x over previous
//
#include <hip/hip_runtime.h>
#include <hip/hip_bf16.h>

#define N_NODESC 50000
#define N_EDGESC 800000
#define DD 128
#define HH 8
#define HDIM 16
#define N_NT 3
#define N_ET 5
#define NPB 196    // node chunks (196*256 = 50176 >= 50000)
#define NEB 400    // edge-pass blocks in kernel A
#define NFB 512    // fill blocks in kernel C

// ---------------- workspace layout (bytes) ----------------
#define KV8_OFF    ((size_t)0)           // fp8 [N][128] {K,V} interleaved ushort, 12.8 MB (orig ids)
#define QT8_OFF    ((size_t)12800000)    // fp8 [N][640] 32 MB (orig ids, dead after edgeagg)
#define XP_OFF     ((size_t)44800000)    // bf16 [N][128] permuted 12.8 MB (dead after proj)
#define T_OFF      ((size_t)0)           // bf16 [N][512] 51.2 MB overlays KV8|Qt8|Xp (dead at ffn1)
#define AGG_OFF    ((size_t)57600000)    // bf16 [N][128] 12.8 MB
#define H1B_OFF    ((size_t)70400000)    // bf16 [N][128] 12.8 MB
#define WOUTT_OFF  ((size_t)83200000)    // bf16 [128][128] 32 KB
#define W1T_OFF    ((size_t)83232768)    // bf16 [512][128] 128 KB
#define W2T_OFF    ((size_t)83363840)    // bf16 [128][512] 128 KB
#define WALL_OFF   ((size_t)83494912)    // bf16 [3][896][128] 672 KB
#define EDATA_OFF  ((size_t)84183040)    // int [E] packed src|et<<16 (orig ids), 3.2 MB
#define ROWS_OFF   ((size_t)87383040)    // int [N+1] (+pad)
#define ORIG_OFF   ((size_t)87583104)    // int [N]
#define DEG_OFF    ((size_t)87783104)    // int [N] (memset 0)
#define TOFS_OFF   ((size_t)87983104)    // int [4]
#define BH_OFF     ((size_t)87983168)    // int [3*NPB]
#define BB_OFF     ((size_t)87985536)    // int [3*NPB]
#define TMP_OFF    ((size_t)87988928)    // uint [E] packed rank<<16|nd, 3.2 MB

using short8 = __attribute__((ext_vector_type(8))) short;
using f32x4  = __attribute__((ext_vector_type(4))) float;

__device__ __forceinline__ ushort f2b(float f) {
    __hip_bfloat16 h = __float2bfloat16(f);
    return *(ushort*)&h;
}
__device__ __forceinline__ float b2f(ushort u) {
    __hip_bfloat16 h = *(__hip_bfloat16*)&u;
    return __bfloat162float(h);
}

// ================= kernel A: wprep (b<1920) | phist (b<2116) | deg+rank (rest) =================
// independent block ranges, no intra-kernel dependency -> no sync needed
__global__ __launch_bounds__(256) void prep_a(
    const float* __restrict__ Wout, const float* __restrict__ W1, const float* __restrict__ W2,
    const float* __restrict__ WQ, const float* __restrict__ Wk, const float* __restrict__ Wv,
    const float* __restrict__ We, const float* __restrict__ mu,
    ushort* __restrict__ Woutt, ushort* __restrict__ W1t, ushort* __restrict__ W2t,
    ushort* __restrict__ Wall,
    const int* __restrict__ ntype, int* __restrict__ bh,
    const int* __restrict__ dst, int* __restrict__ deg, unsigned int* __restrict__ tmp)
{
    const int b = blockIdx.x, tid = threadIdx.x;
    if (b < 1920) {
        // ---- weight prep ----
        const int gid = b * 256 + tid;
        if (gid < 16384) {                       // Woutt[n][k] = Wout[k][n]
            const int nn = gid >> 7, k = gid & 127;
            Woutt[gid] = f2b(Wout[k * 128 + nn]);
        } else if (gid < 81920) {                // W1t[n][k] = W1[k][n]
            const int i = gid - 16384;
            const int nn = i >> 7, k = i & 127;
            W1t[i] = f2b(W1[k * 512 + nn]);
        } else if (gid < 147456) {               // W2t[n][k] = W2[k][n]
            const int i = gid - 81920;
            const int nn = i >> 9, k = i & 511;
            W2t[i] = f2b(W2[k * 128 + nn]);
        } else {                                 // Wall [4K | 4V | Qt et 0..4], block-diag per head
            const int idx = gid - 147456;        // < 344064
            const int t = idx / (896 * 128);
            const int rem = idx % (896 * 128);
            const int c = rem / 128, k = rem % 128;
            const int hk = k >> 4, ck = k & 15;
            float v = 0.f;
            if (c < 128) {
                const int hc = c >> 4, j = c & 15;
                if (hk == hc) v = 4.f * Wk[((t * HH + hc) * HDIM + ck) * HDIM + j];
            } else if (c < 256) {
                const int c2 = c - 128, hc = c2 >> 4, j = c2 & 15;
                if (hk == hc) v = 4.f * Wv[((t * HH + hc) * HDIM + ck) * HDIM + j];
            } else {
                const int cq = c - 256, et = cq >> 7, dd = cq & 127;
                const int hq = dd >> 4, j = dd & 15;
                if (hk == hq) {
                    const float* wq = WQ + ((t * HH + hq) * HDIM + ck) * HDIM;
                    const float* we = We + ((et * HH + hq) * HDIM + j) * HDIM;
                    float s = 0.f;
#pragma unroll
                    for (int f = 0; f < 16; f++) s = fmaf(wq[f], we[f], s);
                    v = 64.f * mu[hq * N_ET + et] * s;   // 64 = 256 fp8 scale * 0.25
                }
            }
            Wall[idx] = f2b(v);
        }
    } else if (b < 1920 + NPB) {
        // ---- per-chunk type histogram ----
        const int bc = b - 1920;
        const int wave = tid >> 6, lane = tid & 63;
        const int n = bc * 256 + tid;
        const int t = (n < N_NODESC) ? ntype[n] : -1;
        const unsigned long long m0 = __ballot(t == 0);
        const unsigned long long m1 = __ballot(t == 1);
        const unsigned long long m2 = __ballot(t == 2);
        __shared__ int wcnt[4][3];
        if (lane == 0) {
            wcnt[wave][0] = (int)__popcll(m0);
            wcnt[wave][1] = (int)__popcll(m1);
            wcnt[wave][2] = (int)__popcll(m2);
        }
        __syncthreads();
        if (tid < 3)
            bh[tid * NPB + bc] = wcnt[0][tid] + wcnt[1][tid] + wcnt[2][tid] + wcnt[3][tid];
    } else {
        // ---- degree count + rank capture (orig dst ids) ----
        for (int e = (b - 1920 - NPB) * 256 + tid; e < N_EDGESC; e += NEB * 256) {
            const int nd = dst[e];
            const unsigned int p = (unsigned int)atomicAdd(&deg[nd], 1);
            tmp[e] = (p << 16) | (unsigned int)nd;
        }
    }
}

// ================= kernel B: permscan (block 0) | rowscan (block 1) =================
__global__ __launch_bounds__(1024) void prep_b(
    const int* __restrict__ bh, const int* __restrict__ deg,
    int* __restrict__ bb, int* __restrict__ tofs, int* __restrict__ rows)
{
    __shared__ int part[1024];
    const int tid = threadIdx.x;
    if (blockIdx.x == 0) {
        // exclusive scan of 3*NPB=588 chunk-type counts -> bb, tofs
        part[tid] = (tid < 3 * NPB) ? bh[tid] : 0;
        __syncthreads();
        for (int off = 1; off < 1024; off <<= 1) {
            const int u = (tid >= off) ? part[tid - off] : 0;
            __syncthreads();
            part[tid] += u;
            __syncthreads();
        }
        const int excl = (tid == 0) ? 0 : part[tid - 1];
        if (tid < 3 * NPB) bb[tid] = excl;
        if (tid == 0) { tofs[0] = 0; tofs[3] = N_NODESC; }
        if (tid == NPB) tofs[1] = excl;
        if (tid == 2 * NPB) tofs[2] = excl;
    } else {
        // exclusive scan of deg (orig ids) -> rows
        const int per = 49;  // 1024*49 >= 50000
        const int base = tid * per;
        int s = 0;
        for (int i = 0; i < per; i++) { int idx = base + i; if (idx < N_NODESC) s += deg[idx]; }
        part[tid] = s;
        __syncthreads();
        for (int off = 1; off < 1024; off <<= 1) {
            int v = (tid >= off) ? part[tid - off] : 0;
            __syncthreads();
            part[tid] += v;
            __syncthreads();
        }
        int run = (tid == 0) ? 0 : part[tid - 1];
        for (int i = 0; i < per; i++) {
            int idx = base + i;
            if (idx < N_NODESC) { rows[idx] = run; run += deg[idx]; }
        }
        if (tid == 1023) rows[N_NODESC] = part[1023];
    }
}

// ================= kernel C: pscatter+Xp (b<NPB) | fill edata (rest) =================
__global__ __launch_bounds__(256) void prep_c(
    const int* __restrict__ ntype, const float* __restrict__ x,
    const int* __restrict__ src, const int* __restrict__ etype,
    const int* __restrict__ bb, const int* __restrict__ rows,
    const unsigned int* __restrict__ tmp,
    int* __restrict__ origof, ushort* __restrict__ Xp, int* __restrict__ edata)
{
    const int b = blockIdx.x, tid = threadIdx.x;
    if (b < NPB) {
        const int wave = tid >> 6, lane = tid & 63;
        const int n = b * 256 + tid;
        const int t = (n < N_NODESC) ? ntype[n] : -1;
        const unsigned long long m0 = __ballot(t == 0);
        const unsigned long long m1 = __ballot(t == 1);
        const unsigned long long m2 = __ballot(t == 2);
        __shared__ int wcnt[4][3];
        __shared__ int sp[256];
        if (lane == 0) {
            wcnt[wave][0] = (int)__popcll(m0);
            wcnt[wave][1] = (int)__popcll(m1);
            wcnt[wave][2] = (int)__popcll(m2);
        }
        __syncthreads();
        int p = -1;
        if (n < N_NODESC) {
            int basew = 0;
#pragma unroll
            for (int w = 0; w < 4; w++) if (w < wave) basew += wcnt[w][t];
            const unsigned long long mt = (t == 0) ? m0 : (t == 1) ? m1 : m2;
            const unsigned long long mlt = ((unsigned long long)1 << lane) - 1;
            p = bb[t * NPB + b] + basew + (int)__popcll(mt & mlt);
            origof[p] = n;
        }
        sp[tid] = p;
        __syncthreads();
        // cooperative permuted bf16 copy: 256 nodes x 16 chunks of 8
        for (int i = tid; i < 256 * 16; i += 256) {
            const int nn = i >> 4, c = (i & 15) << 3;
            const int pp = sp[nn];
            if (pp < 0) continue;
            const int n2 = b * 256 + nn;
            const float4 v0 = *(const float4*)(x + (size_t)n2 * DD + c);
            const float4 v1 = *(const float4*)(x + (size_t)n2 * DD + c + 4);
            ushort o[8] = {f2b(v0.x), f2b(v0.y), f2b(v0.z), f2b(v0.w),
                           f2b(v1.x), f2b(v1.y), f2b(v1.z), f2b(v1.w)};
            *(uint4*)(Xp + (size_t)pp * DD + c) = *(uint4*)o;
        }
    } else {
        // atomic-free fill using captured ranks
        for (int e = (b - NPB) * 256 + tid; e < N_EDGESC; e += NFB * 256) {
            const unsigned int v = tmp[e];
            const int nd = (int)(v & 0xffffu);
            const int p = (int)(v >> 16);
            edata[rows[nd] + p] = src[e] | (etype[e] << 16);
        }
    }
}

// ================= projection GEMM: Xp @ Wall[t] -> KV8 | Qt8 (scatter to orig ids) =================
#define LDP 40

__global__ __launch_bounds__(256) void proj_gemm(
    const ushort* __restrict__ Xp, const ushort* __restrict__ Wall,
    const int* __restrict__ tofs, const int* __restrict__ origof,
    ushort* __restrict__ KV8, unsigned char* __restrict__ Qt8)
{
    const int t = blockIdx.z;
    const int rs = tofs[t], re = tofs[t + 1];
    const int mBase = rs + blockIdx.x * 128;
    if (mBase >= re) return;
    const int nBase = blockIdx.y * 128;
    const ushort* Bt = Wall + (size_t)t * 896 * 128;

    __shared__ ushort As[128 * LDP];
    __shared__ ushort Bs[128 * LDP];
    const int tid = threadIdx.x;
    const int lane = tid & 63, wave = tid >> 6;
    const int mw = (wave >> 1) * 64, nw = (wave & 1) * 64;
    const int l15 = lane & 15, q8 = (lane >> 4) * 8;

    f32x4 acc[4][4];
#pragma unroll
    for (int i = 0; i < 4; i++)
#pragma unroll
        for (int j = 0; j < 4; j++) acc[i][j] = (f32x4){0.f, 0.f, 0.f, 0.f};

    const int r0 = tid >> 2, c0 = (tid & 3) * 8;
    int rA0 = mBase + r0;      if (rA0 >= N_NODESC) rA0 = N_NODESC - 1;
    int rA1 = mBase + r0 + 64; if (rA1 >= N_NODESC) rA1 = N_NODESC - 1;

    for (int kk = 0; kk < 128; kk += 32) {
        short8 a0 = *(const short8*)(Xp + (size_t)rA0 * DD + kk + c0);
        short8 a1 = *(const short8*)(Xp + (size_t)rA1 * DD + kk + c0);
        short8 b0 = *(const short8*)(Bt + (size_t)(nBase + r0) * 128 + kk + c0);
        short8 b1 = *(const short8*)(Bt + (size_t)(nBase + r0 + 64) * 128 + kk + c0);
        *(short8*)&As[r0 * LDP + c0] = a0;
        *(short8*)&As[(r0 + 64) * LDP + c0] = a1;
        *(short8*)&Bs[r0 * LDP + c0] = b0;
        *(short8*)&Bs[(r0 + 64) * LDP + c0] = b1;
        __syncthreads();
        short8 af[4], bf[4];
#pragma unroll
        for (int i = 0; i < 4; i++)
            af[i] = *(const short8*)&As[(mw + i * 16 + l15) * LDP + q8];
#pragma unroll
        for (int j = 0; j < 4; j++)
            bf[j] = *(const short8*)&Bs[(nw + j * 16 + l15) * LDP + q8];
#pragma unroll
        for (int i = 0; i < 4; i++)
#pragma unroll
            for (int j = 0; j < 4; j++)
                acc[i][j] = __builtin_amdgcn_mfma_f32_16x16x32_bf16(af[i], bf[j], acc[i][j], 0, 0, 0);
        __syncthreads();
    }

    unsigned char* kvb = (unsigned char*)KV8;
    const int rq = (lane >> 4) * 4;
#pragma unroll
    for (int i = 0; i < 4; i++) {
#pragma unroll
        for (int r = 0; r < 4; r++) {
            const int gm = mBase + mw + i * 16 + rq + r;
            if (gm >= re) continue;
            const int og = origof[gm];   // scatter outputs to ORIGINAL node id
#pragma unroll
            for (int j = 0; j < 4; j++) {
                const int gn = nBase + nw + j * 16 + l15;
                const float v = acc[i][j][r];
                const unsigned char b8 =
                    (unsigned char)(__builtin_amdgcn_cvt_pk_fp8_f32(v, v, 0, false) & 0xff);
                if (gn < 128)      kvb[(size_t)og * 256 + gn * 2] = b8;             // K byte0
                else if (gn < 256) kvb[(size_t)og * 256 + (gn - 128) * 2 + 1] = b8; // V byte1
                else               Qt8[(size_t)og * 640 + (gn - 256)] = b8;
            }
        }
    }
}

// ================= fused edge pass (orig ids everywhere) =================
#define PROC(ed) { \
    const int s_ = (ed) & 0xffff; \
    const int et_ = (ed) >> 16; \
    const ushort kv_ = KV8[((size_t)s_ << 7) + f]; \
    const float k_ = __builtin_amdgcn_cvt_f32_fp8((int)kv_, 0); \
    const float v_ = __builtin_amdgcn_cvt_f32_fp8((int)kv_, 1); \
    float p_ = qs[(et_ << 7) + f] * k_; \
    p_ += __shfl_xor(p_, 1); p_ += __shfl_xor(p_, 2); \
    p_ += __shfl_xor(p_, 4); p_ += __shfl_xor(p_, 8); \
    const float ex_ = exp2f(p_); \
    den += ex_; acc = fmaf(ex_, v_, acc); }

__global__ __launch_bounds__(128) void edgeagg_kernel(
    const int* __restrict__ rowstart, const int* __restrict__ edata,
    const unsigned char* __restrict__ Qt8, const ushort* __restrict__ KV8,
    ushort* __restrict__ agg)
{
    const int n = blockIdx.x;
    const int f = threadIdx.x;
    __shared__ float qs[N_ET * DD];
    const float qscale = 1.44269504f / 1024.f;   // log2e / 1024 folded into q
#pragma unroll
    for (int et = 0; et < N_ET; et++)
        qs[(et << 7) + f] =
            __builtin_amdgcn_cvt_f32_fp8((int)Qt8[(size_t)n * 640 + (et << 7) + f], 0) * qscale;
    __syncthreads();

    const int s0 = rowstart[n], s1 = rowstart[n + 1];
    float acc = 0.f, den = 0.f;
    int i = s0;
    for (; i + 3 < s1; i += 4) {
        const int e0 = edata[i], e1 = edata[i + 1], e2 = edata[i + 2], e3 = edata[i + 3];
        PROC(e0); PROC(e1); PROC(e2); PROC(e3);
    }
    for (; i < s1; i++) { const int e0 = edata[i]; PROC(e0); }
    agg[(size_t)n * DD + f] = f2b(0.25f * acc / (den + 1e-10f));   // undo V x4 scale
}

// ================= MFMA bf16 GEMM 128x128 tile, BK=32, fused epilogues =================
// EPI 0: T = bf16 gelu(acc + bias); EPI 1: h1b = bf16 LN(acc+bias+residF); EPI 2: out = f32 LN(acc+bias+residB)
template<int KT, int EPI>
__global__ __launch_bounds__(256) void mfma_gemm(
    const ushort* __restrict__ A, const ushort* __restrict__ Bt,
    const float* __restrict__ bias,
    const float* __restrict__ residF, const ushort* __restrict__ residB,
    const float* __restrict__ g, const float* __restrict__ b,
    float* __restrict__ outF, ushort* __restrict__ outB, int ldOut)
{
    __shared__ ushort As[128 * LDP];
    __shared__ ushort Bs[128 * LDP];
    __shared__ float red[2][2][128];
    const int tid = threadIdx.x;
    const int lane = tid & 63, wave = tid >> 6;
    const int mw = (wave >> 1) * 64, nw = (wave & 1) * 64;
    const int mBase = blockIdx.x * 128, nBase = blockIdx.y * 128;
    const int l15 = lane & 15, q8 = (lane >> 4) * 8;

    f32x4 acc[4][4];
#pragma unroll
    for (int i = 0; i < 4; i++)
#pragma unroll
        for (int j = 0; j < 4; j++) acc[i][j] = (f32x4){0.f, 0.f, 0.f, 0.f};

    const int r0 = tid >> 2;
    const int c0 = (tid & 3) * 8;

    for (int kk = 0; kk < KT; kk += 32) {
        const ushort* pa = A  + (size_t)(mBase + r0) * KT + kk + c0;
        const ushort* pb = Bt + (size_t)(nBase + r0) * KT + kk + c0;
        short8 a0 = *(const short8*)pa;
        short8 a1 = *(const short8*)(pa + (size_t)64 * KT);
        short8 b0 = *(const short8*)pb;
        short8 b1 = *(const short8*)(pb + (size_t)64 * KT);
        *(short8*)&As[r0 * LDP + c0] = a0;
        *(short8*)&As[(r0 + 64) * LDP + c0] = a1;
        *(short8*)&Bs[r0 * LDP + c0] = b0;
        *(short8*)&Bs[(r0 + 64) * LDP + c0] = b1;
        __syncthreads();

        short8 af[4], bf[4];
#pragma unroll
        for (int i = 0; i < 4; i++)
            af[i] = *(const short8*)&As[(mw + i * 16 + l15) * LDP + q8];
#pragma unroll
        for (int j = 0; j < 4; j++)
            bf[j] = *(const short8*)&Bs[(nw + j * 16 + l15) * LDP + q8];
#pragma unroll
        for (int i = 0; i < 4; i++)
#pragma unroll
            for (int j = 0; j < 4; j++)
                acc[i][j] = __builtin_amdgcn_mfma_f32_16x16x32_bf16(af[i], bf[j], acc[i][j], 0, 0, 0);
        __syncthreads();
    }

    const int rq = (lane >> 4) * 4;

    if (EPI == 0) {
#pragma unroll
        for (int i = 0; i < 4; i++) {
#pragma unroll
            for (int r = 0; r < 4; r++) {
                const int gm = mBase + mw + i * 16 + rq + r;
                if (gm >= N_NODESC) continue;
#pragma unroll
                for (int j = 0; j < 4; j++) {
                    const int gn = nBase + nw + j * 16 + l15;
                    float v = acc[i][j][r] + bias[gn];
                    v = 0.5f * v * (1.f + erff(v * 0.70710678118654752f));
                    outB[(size_t)gm * ldOut + gn] = f2b(v);
                }
            }
        }
    } else {
        float biasv[4], gv[4], bv[4];
#pragma unroll
        for (int j = 0; j < 4; j++) {
            const int gn = nw + j * 16 + l15;
            biasv[j] = bias[gn]; gv[j] = g[gn]; bv[j] = b[gn];
        }
#pragma unroll
        for (int i = 0; i < 4; i++) {
#pragma unroll
            for (int r = 0; r < 4; r++) {
                const int row = mw + i * 16 + rq + r;
                const int gm = mBase + row;
                float s = 0.f, ss = 0.f;
#pragma unroll
                for (int j = 0; j < 4; j++) {
                    const int gn = nw + j * 16 + l15;
                    float v = acc[i][j][r] + biasv[j];
                    if (EPI == 1) v += (gm < N_NODESC) ? residF[(size_t)gm * DD + gn] : 0.f;
                    else          v += (gm < N_NODESC) ? b2f(residB[(size_t)gm * DD + gn]) : 0.f;
                    acc[i][j][r] = v;
                    s += v; ss += v * v;
                }
                s  += __shfl_xor(s, 1);  s  += __shfl_xor(s, 2);  s  += __shfl_xor(s, 4);  s  += __shfl_xor(s, 8);
                ss += __shfl_xor(ss, 1); ss += __shfl_xor(ss, 2); ss += __shfl_xor(ss, 4); ss += __shfl_xor(ss, 8);
                if (l15 == 0) { red[0][nw >> 6][row] = s; red[1][nw >> 6][row] = ss; }
            }
        }
        __syncthreads();
#pragma unroll
        for (int i = 0; i < 4; i++) {
#pragma unroll
            for (int r = 0; r < 4; r++) {
                const int row = mw + i * 16 + rq + r;
                const int gm = mBase + row;
                if (gm >= N_NODESC) continue;
                const float s  = red[0][0][row] + red[0][1][row];
                const float ss = red[1][0][row] + red[1][1][row];
                const float mean = s * (1.f / 128.f);
                const float var  = ss * (1.f / 128.f) - mean * mean;
                const float rstd = rsqrtf(var + 1e-5f);
#pragma unroll
                for (int j = 0; j < 4; j++) {
                    const int gn = nw + j * 16 + l15;
                    const float o = (acc[i][j][r] - mean) * rstd * gv[j] + bv[j];
                    if (EPI == 1) outB[(size_t)gm * DD + gn] = f2b(o);
                    else          outF[(size_t)gm * DD + gn] = o;
                }
            }
        }
    }
}

extern "C" void kernel_launch(void* const* d_in, const int* in_sizes, int n_in,
                              void* d_out, int out_size, void* d_ws, size_t ws_size,
                              hipStream_t stream)
{
    const float* x     = (const float*)d_in[0];
    const int*   ei    = (const int*)d_in[1];
    const int*   etyp  = (const int*)d_in[2];
    const int*   ntype = (const int*)d_in[3];
    const float* Wq    = (const float*)d_in[4];
    const float* Wk    = (const float*)d_in[5];
    const float* Wv    = (const float*)d_in[6];
    const float* We    = (const float*)d_in[7];
    const float* mu    = (const float*)d_in[8];
    const float* Wout  = (const float*)d_in[9];
    const float* bout  = (const float*)d_in[10];
    const float* g1    = (const float*)d_in[11];
    const float* b1ln  = (const float*)d_in[12];
    const float* W1    = (const float*)d_in[13];
    const float* b1    = (const float*)d_in[14];
    const float* W2    = (const float*)d_in[15];
    const float* b2    = (const float*)d_in[16];
    const float* g2    = (const float*)d_in[17];
    const float* b2ln  = (const float*)d_in[18];
    float* out = (float*)d_out;

    char* ws = (char*)d_ws;
    ushort*        KV8   = (ushort*)(ws + KV8_OFF);
    unsigned char* Qt8   = (unsigned char*)(ws + QT8_OFF);
    ushort*        Xp    = (ushort*)(ws + XP_OFF);
    ushort*        T     = (ushort*)(ws + T_OFF);
    ushort*        agg   = (ushort*)(ws + AGG_OFF);
    ushort*        h1b   = (ushort*)(ws + H1B_OFF);
    ushort*        Woutt = (ushort*)(ws + WOUTT_OFF);
    ushort*        W1t   = (ushort*)(ws + W1T_OFF);
    ushort*        W2t   = (ushort*)(ws + W2T_OFF);
    ushort*        Wall  = (ushort*)(ws + WALL_OFF);
    int*           edata = (int*)(ws + EDATA_OFF);
    int*           rows  = (int*)(ws + ROWS_OFF);
    int*           origof= (int*)(ws + ORIG_OFF);
    int*           deg   = (int*)(ws + DEG_OFF);
    int*           tofs  = (int*)(ws + TOFS_OFF);
    int*           bh    = (int*)(ws + BH_OFF);
    int*           bb    = (int*)(ws + BB_OFF);
    unsigned int*  tmp   = (unsigned int*)(ws + TMP_OFF);

    const int* srcA = ei;
    const int* dstA = ei + N_EDGESC;

    (void)hipMemsetAsync(ws + DEG_OFF, 0, 200000, stream);

    // A: weights | type hist | deg+rank  (independent ranges, one dispatch)
    prep_a<<<1920 + NPB + NEB, 256, 0, stream>>>(
        Wout, W1, W2, Wq, Wk, Wv, We, mu, Woutt, W1t, W2t, Wall,
        ntype, bh, dstA, deg, tmp);
    // B: perm scan | row scan
    prep_b<<<2, 1024, 0, stream>>>(bh, deg, bb, tofs, rows);
    // C: scatter+Xp | fill edata
    prep_c<<<NPB + NFB, 256, 0, stream>>>(ntype, x, srcA, etyp, bb, rows, tmp,
                                          origof, Xp, edata);

    proj_gemm<<<dim3(394, 7, 3), 256, 0, stream>>>(Xp, Wall, tofs, origof, KV8, Qt8);
    edgeagg_kernel<<<N_NODESC, 128, 0, stream>>>(rows, edata, Qt8, KV8, agg);

    // h1b = LN1(agg @ Wout + bout + x)  (bf16)
    mfma_gemm<128, 1><<<391, 256, 0, stream>>>(agg, Woutt, bout, x, nullptr, g1, b1ln, nullptr, h1b, 128);
    // T = gelu(h1b @ W1 + b1)  (bf16)
    mfma_gemm<128, 0><<<dim3(391, 4), 256, 0, stream>>>(h1b, W1t, b1, nullptr, nullptr, nullptr, nullptr, nullptr, T, 512);
    // out = LN2(T @ W2 + b2 + h1b)  (f32)
    mfma_gemm<512, 2><<<391, 256, 0, stream>>>(T, W2t, b2, nullptr, h1b, g2, b2ln, out, nullptr, 128);
}

// Round 10
// 409.482 us; speedup vs baseline: 3.7598x; 1.2094x over previous
//
#include <hip/hip_runtime.h>
#include <hip/hip_bf16.h>

#define N_NODESC 50000
#define N_EDGESC 800000
#define DD 128
#define HH 8
#define HDIM 16
#define N_NT 3
#define N_ET 5
#define NPB 196    // node chunks (196*256 = 50176 >= 50000)
#define NEB 400    // edge-pass blocks in kernel A
#define NFB 512    // fill blocks in kernel C

// ---------------- workspace layout (bytes) ----------------
#define KV8_OFF    ((size_t)0)           // fp8 [N][128] {K,V} interleaved ushort, 12.8 MB (orig ids)
#define QT8_OFF    ((size_t)12800000)    // fp8 [N][640] 32 MB (orig ids, dead after edgeagg)
#define XP_OFF     ((size_t)44800000)    // bf16 [N][128] permuted 12.8 MB (dead after proj)
#define T_OFF      ((size_t)0)           // bf16 [N][512] 51.2 MB overlays KV8|Qt8|Xp (dead at ffn1)
#define AGG_OFF    ((size_t)57600000)    // bf16 [N][128] 12.8 MB
#define H1B_OFF    ((size_t)70400000)    // bf16 [N][128] 12.8 MB
#define WOUTT_OFF  ((size_t)83200000)    // bf16 [128][128] 32 KB
#define W1T_OFF    ((size_t)83232768)    // bf16 [512][128] 128 KB
#define W2T_OFF    ((size_t)83363840)    // bf16 [128][512] 128 KB
#define WALL_OFF   ((size_t)83494912)    // bf16 [3][896][128] 672 KB
#define EDATA_OFF  ((size_t)84183040)    // int [E] packed src|et<<16 (orig ids), 3.2 MB
#define ROWS_OFF   ((size_t)87383040)    // int [N+1] (+pad)
#define ORIG_OFF   ((size_t)87583104)    // int [N]
#define DEG_OFF    ((size_t)87783104)    // int [N] (memset 0)
#define TOFS_OFF   ((size_t)87983104)    // int [4]
#define BH_OFF     ((size_t)87983168)    // int [3*NPB]
#define BB_OFF     ((size_t)87985536)    // int [3*NPB]
#define TMP_OFF    ((size_t)87988928)    // uint [E] packed rank<<16|nd, 3.2 MB
#define RLOC_OFF   ((size_t)91188928)    // int [N+1] chunk-local exclusive deg scan
#define CSUM_OFF   ((size_t)91389056)    // int [NPB] per-chunk deg sums

using short8 = __attribute__((ext_vector_type(8))) short;
using f32x4  = __attribute__((ext_vector_type(4))) float;

__device__ __forceinline__ ushort f2b(float f) {
    __hip_bfloat16 h = __float2bfloat16(f);
    return *(ushort*)&h;
}
__device__ __forceinline__ float b2f(ushort u) {
    __hip_bfloat16 h = *(__hip_bfloat16*)&u;
    return __bfloat162float(h);
}

// ================= kernel A: wprep (b<1920) | phist (b<2116) | deg+rank (rest) =================
__global__ __launch_bounds__(256) void prep_a(
    const float* __restrict__ Wout, const float* __restrict__ W1, const float* __restrict__ W2,
    const float* __restrict__ WQ, const float* __restrict__ Wk, const float* __restrict__ Wv,
    const float* __restrict__ We, const float* __restrict__ mu,
    ushort* __restrict__ Woutt, ushort* __restrict__ W1t, ushort* __restrict__ W2t,
    ushort* __restrict__ Wall,
    const int* __restrict__ ntype, int* __restrict__ bh,
    const int* __restrict__ dst, int* __restrict__ deg, unsigned int* __restrict__ tmp)
{
    const int b = blockIdx.x, tid = threadIdx.x;
    if (b < 1920) {
        const int gid = b * 256 + tid;
        if (gid < 16384) {                       // Woutt[n][k] = Wout[k][n]
            const int nn = gid >> 7, k = gid & 127;
            Woutt[gid] = f2b(Wout[k * 128 + nn]);
        } else if (gid < 81920) {                // W1t[n][k] = W1[k][n]
            const int i = gid - 16384;
            const int nn = i >> 7, k = i & 127;
            W1t[i] = f2b(W1[k * 512 + nn]);
        } else if (gid < 147456) {               // W2t[n][k] = W2[k][n]
            const int i = gid - 81920;
            const int nn = i >> 9, k = i & 511;
            W2t[i] = f2b(W2[k * 128 + nn]);
        } else {                                 // Wall [4K | 4V | Qt et 0..4], block-diag per head
            const int idx = gid - 147456;        // < 344064
            const int t = idx / (896 * 128);
            const int rem = idx % (896 * 128);
            const int c = rem / 128, k = rem % 128;
            const int hk = k >> 4, ck = k & 15;
            float v = 0.f;
            if (c < 128) {
                const int hc = c >> 4, j = c & 15;
                if (hk == hc) v = 4.f * Wk[((t * HH + hc) * HDIM + ck) * HDIM + j];
            } else if (c < 256) {
                const int c2 = c - 128, hc = c2 >> 4, j = c2 & 15;
                if (hk == hc) v = 4.f * Wv[((t * HH + hc) * HDIM + ck) * HDIM + j];
            } else {
                const int cq = c - 256, et = cq >> 7, dd = cq & 127;
                const int hq = dd >> 4, j = dd & 15;
                if (hk == hq) {
                    const float* wq = WQ + ((t * HH + hq) * HDIM + ck) * HDIM;
                    const float* we = We + ((et * HH + hq) * HDIM + j) * HDIM;
                    float s = 0.f;
#pragma unroll
                    for (int f = 0; f < 16; f++) s = fmaf(wq[f], we[f], s);
                    v = 64.f * mu[hq * N_ET + et] * s;   // 64 = 256 fp8 scale * 0.25
                }
            }
            Wall[idx] = f2b(v);
        }
    } else if (b < 1920 + NPB) {
        const int bc = b - 1920;
        const int wave = tid >> 6, lane = tid & 63;
        const int n = bc * 256 + tid;
        const int t = (n < N_NODESC) ? ntype[n] : -1;
        const unsigned long long m0 = __ballot(t == 0);
        const unsigned long long m1 = __ballot(t == 1);
        const unsigned long long m2 = __ballot(t == 2);
        __shared__ int wcnt[4][3];
        if (lane == 0) {
            wcnt[wave][0] = (int)__popcll(m0);
            wcnt[wave][1] = (int)__popcll(m1);
            wcnt[wave][2] = (int)__popcll(m2);
        }
        __syncthreads();
        if (tid < 3)
            bh[tid * NPB + bc] = wcnt[0][tid] + wcnt[1][tid] + wcnt[2][tid] + wcnt[3][tid];
    } else {
        for (int e = (b - 1920 - NPB) * 256 + tid; e < N_EDGESC; e += NEB * 256) {
            const int nd = dst[e];
            const unsigned int p = (unsigned int)atomicAdd(&deg[nd], 1);
            tmp[e] = (p << 16) | (unsigned int)nd;
        }
    }
}

// ================= kernel B: permscan (block 0) | WIDE chunk-local deg scans (1..196) ============
__global__ __launch_bounds__(256) void prep_b(
    const int* __restrict__ bh, const int* __restrict__ deg,
    int* __restrict__ bb, int* __restrict__ tofs,
    int* __restrict__ rloc, int* __restrict__ csum)
{
    __shared__ int part[256];
    const int tid = threadIdx.x;
    if (blockIdx.x == 0) {
        // exclusive scan of 3*NPB=588 entries: 3 per thread
        const int base3 = tid * 3;
        int e0 = (base3 + 0 < 588) ? bh[base3 + 0] : 0;
        int e1 = (base3 + 1 < 588) ? bh[base3 + 1] : 0;
        int e2 = (base3 + 2 < 588) ? bh[base3 + 2] : 0;
        const int l0 = e0, l1 = e0 + e1, l2 = l1 + e2;
        part[tid] = l2;
        __syncthreads();
        for (int off = 1; off < 256; off <<= 1) {
            const int u = (tid >= off) ? part[tid - off] : 0;
            __syncthreads();
            part[tid] += u;
            __syncthreads();
        }
        const int tb = part[tid] - l2;
        if (base3 + 0 < 588) bb[base3 + 0] = tb;
        if (base3 + 1 < 588) bb[base3 + 1] = tb + l0;
        if (base3 + 2 < 588) bb[base3 + 2] = tb + l1;
        __syncthreads();
        if (tid == 0) {
            tofs[0] = 0;
            tofs[1] = bb[NPB];
            tofs[2] = bb[2 * NPB];
            tofs[3] = N_NODESC;
        }
    } else {
        // chunk-local exclusive scan (coalesced): chunk c covers nodes c*256..c*256+255
        const int c = blockIdx.x - 1;
        const int n = c * 256 + tid;
        const int vdeg = (n < N_NODESC) ? deg[n] : 0;
        part[tid] = vdeg;
        __syncthreads();
        for (int off = 1; off < 256; off <<= 1) {
            const int u = (tid >= off) ? part[tid - off] : 0;
            __syncthreads();
            part[tid] += u;
            __syncthreads();
        }
        if (n <= N_NODESC) rloc[n] = part[tid] - vdeg;   // includes rloc[N]
        if (tid == 255) csum[c] = part[255];
    }
}

// ================= kernel C: pscatter+Xp+rows (b<NPB) | fill edata (rest) =================
__global__ __launch_bounds__(256) void prep_c(
    const int* __restrict__ ntype, const float* __restrict__ x,
    const int* __restrict__ src, const int* __restrict__ etype,
    const int* __restrict__ bb, const int* __restrict__ rloc, const int* __restrict__ csum,
    const unsigned int* __restrict__ tmp,
    int* __restrict__ origof, ushort* __restrict__ Xp, int* __restrict__ rows,
    int* __restrict__ edata)
{
    const int b = blockIdx.x, tid = threadIdx.x;
    __shared__ int cb[256];   // exclusive chunk bases
    // every block: LDS scan of csum[196] -> exclusive bases (tiny, redundant, parallel)
    {
        const int v = (tid < NPB) ? csum[tid] : 0;
        cb[tid] = v;
        __syncthreads();
        for (int off = 1; off < 256; off <<= 1) {
            const int u = (tid >= off) ? cb[tid - off] : 0;
            __syncthreads();
            cb[tid] += u;
            __syncthreads();
        }
        const int incl = cb[tid];
        __syncthreads();
        cb[tid] = incl - v;   // exclusive
        __syncthreads();
    }

    if (b < NPB) {
        const int wave = tid >> 6, lane = tid & 63;
        const int n = b * 256 + tid;
        const int t = (n < N_NODESC) ? ntype[n] : -1;
        const unsigned long long m0 = __ballot(t == 0);
        const unsigned long long m1 = __ballot(t == 1);
        const unsigned long long m2 = __ballot(t == 2);
        __shared__ int wcnt[4][3];
        __shared__ int sp[256];
        if (lane == 0) {
            wcnt[wave][0] = (int)__popcll(m0);
            wcnt[wave][1] = (int)__popcll(m1);
            wcnt[wave][2] = (int)__popcll(m2);
        }
        __syncthreads();
        int p = -1;
        if (n < N_NODESC) {
            int basew = 0;
#pragma unroll
            for (int w = 0; w < 4; w++) if (w < wave) basew += wcnt[w][t];
            const unsigned long long mt = (t == 0) ? m0 : (t == 1) ? m1 : m2;
            const unsigned long long mlt = ((unsigned long long)1 << lane) - 1;
            p = bb[t * NPB + b] + basew + (int)__popcll(mt & mlt);
            origof[p] = n;
        }
        // final rows for this chunk (rloc[n] + chunk base); includes rows[N] from chunk 195
        if (n <= N_NODESC) rows[n] = cb[b] + rloc[n];
        sp[tid] = p;
        __syncthreads();
        // cooperative permuted bf16 copy: 256 nodes x 16 chunks of 8
        for (int i = tid; i < 256 * 16; i += 256) {
            const int nn = i >> 4, c = (i & 15) << 3;
            const int pp = sp[nn];
            if (pp < 0) continue;
            const int n2 = b * 256 + nn;
            const float4 v0 = *(const float4*)(x + (size_t)n2 * DD + c);
            const float4 v1 = *(const float4*)(x + (size_t)n2 * DD + c + 4);
            ushort o[8] = {f2b(v0.x), f2b(v0.y), f2b(v0.z), f2b(v0.w),
                           f2b(v1.x), f2b(v1.y), f2b(v1.z), f2b(v1.w)};
            *(uint4*)(Xp + (size_t)pp * DD + c) = *(uint4*)o;
        }
    } else {
        // atomic-free fill using captured ranks; rowstart = cb[chunk] + rloc[nd]
        for (int e = (b - NPB) * 256 + tid; e < N_EDGESC; e += NFB * 256) {
            const unsigned int v = tmp[e];
            const int nd = (int)(v & 0xffffu);
            const int p = (int)(v >> 16);
            edata[cb[nd >> 8] + rloc[nd] + p] = src[e] | (etype[e] << 16);
        }
    }
}

// ================= projection GEMM: Xp @ Wall[t] -> KV8 | Qt8 (scatter to orig ids) =================
#define LDP 40

__global__ __launch_bounds__(256) void proj_gemm(
    const ushort* __restrict__ Xp, const ushort* __restrict__ Wall,
    const int* __restrict__ tofs, const int* __restrict__ origof,
    ushort* __restrict__ KV8, unsigned char* __restrict__ Qt8)
{
    const int t = blockIdx.z;
    const int rs = tofs[t], re = tofs[t + 1];
    const int mBase = rs + blockIdx.x * 128;
    if (mBase >= re) return;
    const int nBase = blockIdx.y * 128;
    const ushort* Bt = Wall + (size_t)t * 896 * 128;

    __shared__ ushort As[128 * LDP];
    __shared__ ushort Bs[128 * LDP];
    const int tid = threadIdx.x;
    const int lane = tid & 63, wave = tid >> 6;
    const int mw = (wave >> 1) * 64, nw = (wave & 1) * 64;
    const int l15 = lane & 15, q8 = (lane >> 4) * 8;

    f32x4 acc[4][4];
#pragma unroll
    for (int i = 0; i < 4; i++)
#pragma unroll
        for (int j = 0; j < 4; j++) acc[i][j] = (f32x4){0.f, 0.f, 0.f, 0.f};

    const int r0 = tid >> 2, c0 = (tid & 3) * 8;
    int rA0 = mBase + r0;      if (rA0 >= N_NODESC) rA0 = N_NODESC - 1;
    int rA1 = mBase + r0 + 64; if (rA1 >= N_NODESC) rA1 = N_NODESC - 1;

    for (int kk = 0; kk < 128; kk += 32) {
        short8 a0 = *(const short8*)(Xp + (size_t)rA0 * DD + kk + c0);
        short8 a1 = *(const short8*)(Xp + (size_t)rA1 * DD + kk + c0);
        short8 b0 = *(const short8*)(Bt + (size_t)(nBase + r0) * 128 + kk + c0);
        short8 b1 = *(const short8*)(Bt + (size_t)(nBase + r0 + 64) * 128 + kk + c0);
        *(short8*)&As[r0 * LDP + c0] = a0;
        *(short8*)&As[(r0 + 64) * LDP + c0] = a1;
        *(short8*)&Bs[r0 * LDP + c0] = b0;
        *(short8*)&Bs[(r0 + 64) * LDP + c0] = b1;
        __syncthreads();
        short8 af[4], bf[4];
#pragma unroll
        for (int i = 0; i < 4; i++)
            af[i] = *(const short8*)&As[(mw + i * 16 + l15) * LDP + q8];
#pragma unroll
        for (int j = 0; j < 4; j++)
            bf[j] = *(const short8*)&Bs[(nw + j * 16 + l15) * LDP + q8];
#pragma unroll
        for (int i = 0; i < 4; i++)
#pragma unroll
            for (int j = 0; j < 4; j++)
                acc[i][j] = __builtin_amdgcn_mfma_f32_16x16x32_bf16(af[i], bf[j], acc[i][j], 0, 0, 0);
        __syncthreads();
    }

    unsigned char* kvb = (unsigned char*)KV8;
    const int rq = (lane >> 4) * 4;
#pragma unroll
    for (int i = 0; i < 4; i++) {
#pragma unroll
        for (int r = 0; r < 4; r++) {
            const int gm = mBase + mw + i * 16 + rq + r;
            if (gm >= re) continue;
            const int og = origof[gm];   // scatter outputs to ORIGINAL node id
#pragma unroll
            for (int j = 0; j < 4; j++) {
                const int gn = nBase + nw + j * 16 + l15;
                const float v = acc[i][j][r];
                const unsigned char b8 =
                    (unsigned char)(__builtin_amdgcn_cvt_pk_fp8_f32(v, v, 0, false) & 0xff);
                if (gn < 128)      kvb[(size_t)og * 256 + gn * 2] = b8;             // K byte0
                else if (gn < 256) kvb[(size_t)og * 256 + (gn - 128) * 2 + 1] = b8; // V byte1
                else               Qt8[(size_t)og * 640 + (gn - 256)] = b8;
            }
        }
    }
}

// ================= fused edge pass (orig ids everywhere) =================
#define PROC(ed) { \
    const int s_ = (ed) & 0xffff; \
    const int et_ = (ed) >> 16; \
    const ushort kv_ = KV8[((size_t)s_ << 7) + f]; \
    const float k_ = __builtin_amdgcn_cvt_f32_fp8((int)kv_, 0); \
    const float v_ = __builtin_amdgcn_cvt_f32_fp8((int)kv_, 1); \
    float p_ = qs[(et_ << 7) + f] * k_; \
    p_ += __shfl_xor(p_, 1); p_ += __shfl_xor(p_, 2); \
    p_ += __shfl_xor(p_, 4); p_ += __shfl_xor(p_, 8); \
    const float ex_ = exp2f(p_); \
    den += ex_; acc = fmaf(ex_, v_, acc); }

__global__ __launch_bounds__(128) void edgeagg_kernel(
    const int* __restrict__ rowstart, const int* __restrict__ edata,
    const unsigned char* __restrict__ Qt8, const ushort* __restrict__ KV8,
    ushort* __restrict__ agg)
{
    const int n = blockIdx.x;
    const int f = threadIdx.x;
    __shared__ float qs[N_ET * DD];
    const float qscale = 1.44269504f / 1024.f;   // log2e / 1024 folded into q
#pragma unroll
    for (int et = 0; et < N_ET; et++)
        qs[(et << 7) + f] =
            __builtin_amdgcn_cvt_f32_fp8((int)Qt8[(size_t)n * 640 + (et << 7) + f], 0) * qscale;
    __syncthreads();

    const int s0 = rowstart[n], s1 = rowstart[n + 1];
    float acc = 0.f, den = 0.f;
    int i = s0;
    for (; i + 3 < s1; i += 4) {
        const int e0 = edata[i], e1 = edata[i + 1], e2 = edata[i + 2], e3 = edata[i + 3];
        PROC(e0); PROC(e1); PROC(e2); PROC(e3);
    }
    for (; i < s1; i++) { const int e0 = edata[i]; PROC(e0); }
    agg[(size_t)n * DD + f] = f2b(0.25f * acc / (den + 1e-10f));   // undo V x4 scale
}

// ================= MFMA bf16 GEMM 128x128 tile, BK=32, fused epilogues =================
// EPI 0: T = bf16 gelu(acc + bias); EPI 1: h1b = bf16 LN(acc+bias+residF); EPI 2: out = f32 LN(acc+bias+residB)
template<int KT, int EPI>
__global__ __launch_bounds__(256) void mfma_gemm(
    const ushort* __restrict__ A, const ushort* __restrict__ Bt,
    const float* __restrict__ bias,
    const float* __restrict__ residF, const ushort* __restrict__ residB,
    const float* __restrict__ g, const float* __restrict__ b,
    float* __restrict__ outF, ushort* __restrict__ outB, int ldOut)
{
    __shared__ ushort As[128 * LDP];
    __shared__ ushort Bs[128 * LDP];
    __shared__ float red[2][2][128];
    const int tid = threadIdx.x;
    const int lane = tid & 63, wave = tid >> 6;
    const int mw = (wave >> 1) * 64, nw = (wave & 1) * 64;
    const int mBase = blockIdx.x * 128, nBase = blockIdx.y * 128;
    const int l15 = lane & 15, q8 = (lane >> 4) * 8;

    f32x4 acc[4][4];
#pragma unroll
    for (int i = 0; i < 4; i++)
#pragma unroll
        for (int j = 0; j < 4; j++) acc[i][j] = (f32x4){0.f, 0.f, 0.f, 0.f};

    const int r0 = tid >> 2;
    const int c0 = (tid & 3) * 8;

    for (int kk = 0; kk < KT; kk += 32) {
        const ushort* pa = A  + (size_t)(mBase + r0) * KT + kk + c0;
        const ushort* pb = Bt + (size_t)(nBase + r0) * KT + kk + c0;
        short8 a0 = *(const short8*)pa;
        short8 a1 = *(const short8*)(pa + (size_t)64 * KT);
        short8 b0 = *(const short8*)pb;
        short8 b1 = *(const short8*)(pb + (size_t)64 * KT);
        *(short8*)&As[r0 * LDP + c0] = a0;
        *(short8*)&As[(r0 + 64) * LDP + c0] = a1;
        *(short8*)&Bs[r0 * LDP + c0] = b0;
        *(short8*)&Bs[(r0 + 64) * LDP + c0] = b1;
        __syncthreads();

        short8 af[4], bf[4];
#pragma unroll
        for (int i = 0; i < 4; i++)
            af[i] = *(const short8*)&As[(mw + i * 16 + l15) * LDP + q8];
#pragma unroll
        for (int j = 0; j < 4; j++)
            bf[j] = *(const short8*)&Bs[(nw + j * 16 + l15) * LDP + q8];
#pragma unroll
        for (int i = 0; i < 4; i++)
#pragma unroll
            for (int j = 0; j < 4; j++)
                acc[i][j] = __builtin_amdgcn_mfma_f32_16x16x32_bf16(af[i], bf[j], acc[i][j], 0, 0, 0);
        __syncthreads();
    }

    const int rq = (lane >> 4) * 4;

    if (EPI == 0) {
#pragma unroll
        for (int i = 0; i < 4; i++) {
#pragma unroll
            for (int r = 0; r < 4; r++) {
                const int gm = mBase + mw + i * 16 + rq + r;
                if (gm >= N_NODESC) continue;
#pragma unroll
                for (int j = 0; j < 4; j++) {
                    const int gn = nBase + nw + j * 16 + l15;
                    float v = acc[i][j][r] + bias[gn];
                    v = 0.5f * v * (1.f + erff(v * 0.70710678118654752f));
                    outB[(size_t)gm * ldOut + gn] = f2b(v);
                }
            }
        }
    } else {
        float biasv[4], gv[4], bv[4];
#pragma unroll
        for (int j = 0; j < 4; j++) {
            const int gn = nw + j * 16 + l15;
            biasv[j] = bias[gn]; gv[j] = g[gn]; bv[j] = b[gn];
        }
#pragma unroll
        for (int i = 0; i < 4; i++) {
#pragma unroll
            for (int r = 0; r < 4; r++) {
                const int row = mw + i * 16 + rq + r;
                const int gm = mBase + row;
                float s = 0.f, ss = 0.f;
#pragma unroll
                for (int j = 0; j < 4; j++) {
                    const int gn = nw + j * 16 + l15;
                    float v = acc[i][j][r] + biasv[j];
                    if (EPI == 1) v += (gm < N_NODESC) ? residF[(size_t)gm * DD + gn] : 0.f;
                    else          v += (gm < N_NODESC) ? b2f(residB[(size_t)gm * DD + gn]) : 0.f;
                    acc[i][j][r] = v;
                    s += v; ss += v * v;
                }
                s  += __shfl_xor(s, 1);  s  += __shfl_xor(s, 2);  s  += __shfl_xor(s, 4);  s  += __shfl_xor(s, 8);
                ss += __shfl_xor(ss, 1); ss += __shfl_xor(ss, 2); ss += __shfl_xor(ss, 4); ss += __shfl_xor(ss, 8);
                if (l15 == 0) { red[0][nw >> 6][row] = s; red[1][nw >> 6][row] = ss; }
            }
        }
        __syncthreads();
#pragma unroll
        for (int i = 0; i < 4; i++) {
#pragma unroll
            for (int r = 0; r < 4; r++) {
                const int row = mw + i * 16 + rq + r;
                const int gm = mBase + row;
                if (gm >= N_NODESC) continue;
                const float s  = red[0][0][row] + red[0][1][row];
                const float ss = red[1][0][row] + red[1][1][row];
                const float mean = s * (1.f / 128.f);
                const float var  = ss * (1.f / 128.f) - mean * mean;
                const float rstd = rsqrtf(var + 1e-5f);
#pragma unroll
                for (int j = 0; j < 4; j++) {
                    const int gn = nw + j * 16 + l15;
                    const float o = (acc[i][j][r] - mean) * rstd * gv[j] + bv[j];
                    if (EPI == 1) outB[(size_t)gm * DD + gn] = f2b(o);
                    else          outF[(size_t)gm * DD + gn] = o;
                }
            }
        }
    }
}

extern "C" void kernel_launch(void* const* d_in, const int* in_sizes, int n_in,
                              void* d_out, int out_size, void* d_ws, size_t ws_size,
                              hipStream_t stream)
{
    const float* x     = (const float*)d_in[0];
    const int*   ei    = (const int*)d_in[1];
    const int*   etyp  = (const int*)d_in[2];
    const int*   ntype = (const int*)d_in[3];
    const float* Wq    = (const float*)d_in[4];
    const float* Wk    = (const float*)d_in[5];
    const float* Wv    = (const float*)d_in[6];
    const float* We    = (const float*)d_in[7];
    const float* mu    = (const float*)d_in[8];
    const float* Wout  = (const float*)d_in[9];
    const float* bout  = (const float*)d_in[10];
    const float* g1    = (const float*)d_in[11];
    const float* b1ln  = (const float*)d_in[12];
    const float* W1    = (const float*)d_in[13];
    const float* b1    = (const float*)d_in[14];
    const float* W2    = (const float*)d_in[15];
    const float* b2    = (const float*)d_in[16];
    const float* g2    = (const float*)d_in[17];
    const float* b2ln  = (const float*)d_in[18];
    float* out = (float*)d_out;

    char* ws = (char*)d_ws;
    ushort*        KV8   = (ushort*)(ws + KV8_OFF);
    unsigned char* Qt8   = (unsigned char*)(ws + QT8_OFF);
    ushort*        Xp    = (ushort*)(ws + XP_OFF);
    ushort*        T     = (ushort*)(ws + T_OFF);
    ushort*        agg   = (ushort*)(ws + AGG_OFF);
    ushort*        h1b   = (ushort*)(ws + H1B_OFF);
    ushort*        Woutt = (ushort*)(ws + WOUTT_OFF);
    ushort*        W1t   = (ushort*)(ws + W1T_OFF);
    ushort*        W2t   = (ushort*)(ws + W2T_OFF);
    ushort*        Wall  = (ushort*)(ws + WALL_OFF);
    int*           edata = (int*)(ws + EDATA_OFF);
    int*           rows  = (int*)(ws + ROWS_OFF);
    int*           origof= (int*)(ws + ORIG_OFF);
    int*           deg   = (int*)(ws + DEG_OFF);
    int*           tofs  = (int*)(ws + TOFS_OFF);
    int*           bh    = (int*)(ws + BH_OFF);
    int*           bb    = (int*)(ws + BB_OFF);
    unsigned int*  tmp   = (unsigned int*)(ws + TMP_OFF);
    int*           rloc  = (int*)(ws + RLOC_OFF);
    int*           csum  = (int*)(ws + CSUM_OFF);

    const int* srcA = ei;
    const int* dstA = ei + N_EDGESC;

    (void)hipMemsetAsync(ws + DEG_OFF, 0, 200000, stream);

    // A: weights | type hist | deg+rank  (independent ranges, one dispatch)
    prep_a<<<1920 + NPB + NEB, 256, 0, stream>>>(
        Wout, W1, W2, Wq, Wk, Wv, We, mu, Woutt, W1t, W2t, Wall,
        ntype, bh, dstA, deg, tmp);
    // B: perm scan | wide chunk-local deg scans
    prep_b<<<1 + NPB, 256, 0, stream>>>(bh, deg, bb, tofs, rloc, csum);
    // C: scatter+Xp+rows | fill edata
    prep_c<<<NPB + NFB, 256, 0, stream>>>(ntype, x, srcA, etyp, bb, rloc, csum, tmp,
                                          origof, Xp, rows, edata);

    proj_gemm<<<dim3(394, 7, 3), 256, 0, stream>>>(Xp, Wall, tofs, origof, KV8, Qt8);
    edgeagg_kernel<<<N_NODESC, 128, 0, stream>>>(rows, edata, Qt8, KV8, agg);

    // h1b = LN1(agg @ Wout + bout + x)  (bf16)
    mfma_gemm<128, 1><<<391, 256, 0, stream>>>(agg, Woutt, bout, x, nullptr, g1, b1ln, nullptr, h1b, 128);
    // T = gelu(h1b @ W1 + b1)  (bf16)
    mfma_gemm<128, 0><<<dim3(391, 4), 256, 0, stream>>>(h1b, W1t, b1, nullptr, nullptr, nullptr, nullptr, nullptr, T, 512);
    // out = LN2(T @ W2 + b2 + h1b)  (f32)
    mfma_gemm<512, 2><<<391, 256, 0, stream>>>(T, W2t, b2, nullptr, h1b, g2, b2ln, out, nullptr, 128);
}